// Round 4
// baseline (248.332 us; speedup 1.0000x reference)
//
#include <hip/hip_runtime.h>
#include <hip/hip_bf16.h>

#define NN     4096
#define NE     5
#define NC     2
#define FINF   128
#define FOUTF  64
#define CAP    512    // slots per column (4 segments of SEGCAP)
#define SEGCAP 128
#define USPLIT 4
#define YP     132    // fp32 Y panel pitch (128 feats + denom at [128])
#define VB     16     // columns per gcn_out block

// ---------------- workspace layout (bytes) ----------------
// cnt2 @ 0        : NN*4*4    = 65536
// eu   @ 65536    : NN*CAP*4  = 8388608
// wA   @ 8454144  : NN*CAP*8  = 16777216
// wB   @ 25231360 : 16777216
// wC   @ 42008576 : 16777216
// YA   @ 58785792 : NC*NN*YP*4 = 4325376
// Y1   @ 63111168 : 4325376
// Y2   @ 67436544 : 4325376
// DdA  @ 71761920 : 32768
// Dd1  @ 71794688 : 32768
// hb   @ 71827456 : NN*FINF*2 = 1048576
// XbA  @ 72876032 : NC*NN*FINF*2 = 2097152
// Xb1  @ 74973184 : 2097152
// end ~ 77.1 MB

static __device__ __forceinline__ unsigned bf16bits(float x)
{
    __hip_bfloat16 t = __float2bfloat16(x);
    return (unsigned)*reinterpret_cast<unsigned short*>(&t);
}

__global__ __launch_bounds__(256) void h2b(const float4* __restrict__ h4,
                                           uint2* __restrict__ hb)
{
    int i = blockIdx.x * 256 + threadIdx.x;     // 131072 float4s
    float4 f = h4[i];
    uint2 r;
    r.x = bf16bits(f.x) | (bf16bits(f.y) << 16);
    r.y = bf16bits(f.z) | (bf16bits(f.w) << 16);
    hb[i] = r;
}

// Column-local CSC build: no global atomics, deterministic segments.
// Grid: 256 v-blocks (16 columns each) x USPLIT u-ranges.
__global__ __launch_bounds__(256) void build_csc(
    const float* __restrict__ A,
    const float* __restrict__ W1_0,
    const float* __restrict__ W2_0,
    const float* __restrict__ W1_1,
    int*    __restrict__ cnt2,   // [NN][USPLIT]
    int*    __restrict__ eu,     // [NN][CAP]
    float2* __restrict__ wA,
    float2* __restrict__ wB,
    float2* __restrict__ wC)
{
    __shared__ int lcnt[16];
    int tid = threadIdx.x;
    if (tid < 16) lcnt[tid] = 0;
    __syncthreads();

    int vb = blockIdx.x & 255;
    int us = blockIdx.x >> 8;
    int vbase = vb * 16;
    int u0 = us * (NN / USPLIT);

    float fA0[NE], fA1[NE], fB0[NE], fB1[NE], fC0[NE], fC1[NE];
#pragma unroll
    for (int e = 0; e < NE; ++e) {
        fA0[e] = W1_0[e];      fA1[e] = W1_0[NE + e];
        fB0[e] = W2_0[e];      fB1[e] = W2_0[NE + e];
        fC0[e] = W1_1[e];      fC1[e] = W1_1[NE + e];
    }

    const size_t SL = (size_t)NN * NN;   // floats per e-slice
    int du = tid >> 2, dv4 = tid & 3;

    for (int chunk = 0; chunk < (NN / USPLIT) / 64; ++chunk) {
        int u = u0 + chunk * 64 + du;
        const float* base = A + (size_t)u * NN + vbase + dv4 * 4;
        float4 q0 = *(const float4*)(base);
        float4 q1 = *(const float4*)(base + SL);
        float4 q2 = *(const float4*)(base + 2 * SL);
        float4 q3 = *(const float4*)(base + 3 * SL);
        float4 q4 = *(const float4*)(base + 4 * SL);
#define DO_COMP(comp, j)                                                         \
        {                                                                        \
            float a0 = q0.comp, a1 = q1.comp, a2 = q2.comp,                      \
                  a3 = q3.comp, a4 = q4.comp;                                    \
            if (a0 != 0.f || a1 != 0.f || a2 != 0.f || a3 != 0.f || a4 != 0.f) { \
                float sA0 = fA0[0]*a0 + fA0[1]*a1 + fA0[2]*a2 + fA0[3]*a3 + fA0[4]*a4; \
                float sA1 = fA1[0]*a0 + fA1[1]*a1 + fA1[2]*a2 + fA1[3]*a3 + fA1[4]*a4; \
                float sB0 = fB0[0]*a0 + fB0[1]*a1 + fB0[2]*a2 + fB0[3]*a3 + fB0[4]*a4; \
                float sB1 = fB1[0]*a0 + fB1[1]*a1 + fB1[2]*a2 + fB1[3]*a3 + fB1[4]*a4; \
                float sC0 = fC0[0]*a0 + fC0[1]*a1 + fC0[2]*a2 + fC0[3]*a3 + fC0[4]*a4; \
                float sC1 = fC1[0]*a0 + fC1[1]*a1 + fC1[2]*a2 + fC1[3]*a3 + fC1[4]*a4; \
                int lc = dv4 * 4 + j;                                            \
                int pos = atomicAdd(&lcnt[lc], 1);     /* LDS atomic */          \
                if (pos < SEGCAP) {                                              \
                    int slot = (vbase + lc) * CAP + us * SEGCAP + pos;           \
                    eu[slot] = u;                                                \
                    wA[slot] = float2{__expf(sA0), __expf(sA1)};                 \
                    wB[slot] = float2{__expf(sB0), __expf(sB1)};                 \
                    wC[slot] = float2{sC0, sC1};                                 \
                }                                                                \
            }                                                                    \
        }
        DO_COMP(x, 0)
        DO_COMP(y, 1)
        DO_COMP(z, 2)
        DO_COMP(w, 3)
#undef DO_COMP
    }
    __syncthreads();
    if (tid < 16) {
        int c = lcnt[tid];
        cnt2[(vbase + tid) * USPLIT + us] = c < SEGCAP ? c : SEGCAP;
    }
}

// One workgroup (256 threads) per column v; both channels.
// Phase 1: concatenate 4 edge segments into LDS, reduce weight-sums + denoms.
// Phase 2: 8 edge-groups x 32 lanes, bf16x4 row gathers, LDS tree reduce.
// STAGE 0: gather hb (bf16, shared by channels), softmax-norm, denom = sum(w)
// STAGE 1: gather bf16 panel per channel, softmax-norm, denom from Dd_in
// STAGE 2: gather bf16 panel per channel, no norm, denom from Dd_in
template<int STAGE>
__global__ __launch_bounds__(256) void spmm_col(
    const int*    __restrict__ cnt2,
    const int*    __restrict__ eu,
    const float2* __restrict__ ew,
    const uint2*  __restrict__ Xb_in,   // stage0: [NN][32]; else [NC][NN][32]
    const float*  __restrict__ Dd_in,   // stages 1/2: [NC][NN]
    float*        __restrict__ Y,       // [NC][NN][YP]
    ushort*       __restrict__ Xb_out,  // stages 0/1
    float*        __restrict__ Dd_out)  // stages 0/1
{
    int v = blockIdx.x;
    int ns0 = cnt2[v * USPLIT + 0];
    int ns1 = cnt2[v * USPLIT + 1];
    int ns2 = cnt2[v * USPLIT + 2];
    int ns3 = cnt2[v * USPLIT + 3];
    int sb1 = ns0, sb2 = ns0 + ns1, sb3 = sb2 + ns2;
    int n = sb3 + ns3;

    __shared__ float4 s_e[CAP];
    __shared__ float  s_red[4];
    __shared__ float4 s_acc[NC][8][32];

    int tid = threadIdx.x;
    if (tid < 4) s_red[tid] = 0.f;
    __syncthreads();

    float l0 = 0.f, l1 = 0.f, ld0 = 0.f, ld1 = 0.f;
#pragma unroll
    for (int s = 0; s < USPLIT; ++s) {
        int ns    = (s == 0) ? ns0 : (s == 1) ? ns1 : (s == 2) ? ns2 : ns3;
        int sbase = (s == 0) ? 0   : (s == 1) ? sb1 : (s == 2) ? sb2 : sb3;
        int gbase = v * CAP + s * SEGCAP;
        for (int i = tid; i < ns; i += 256) {
            int    u = eu[gbase + i];
            float2 w = ew[gbase + i];
            s_e[sbase + i] = float4{__int_as_float(u), w.x, w.y, 0.f};
            l0 += w.x;
            l1 += w.y;
            if (STAGE != 0) {
                ld0 += w.x * Dd_in[u];
                ld1 += w.y * Dd_in[NN + u];
            }
        }
    }
    if (STAGE == 0) { ld0 = l0; ld1 = l1; }

#pragma unroll
    for (int m = 32; m >= 1; m >>= 1) {
        l0  += __shfl_xor(l0,  m);
        l1  += __shfl_xor(l1,  m);
        ld0 += __shfl_xor(ld0, m);
        ld1 += __shfl_xor(ld1, m);
    }
    if ((tid & 63) == 0) {
        atomicAdd(&s_red[0], l0);
        atomicAdd(&s_red[1], l1);
        atomicAdd(&s_red[2], ld0);
        atomicAdd(&s_red[3], ld1);
    }
    __syncthreads();

    int grp = tid >> 5, lane = tid & 31;
    float4 a0 = {0.f, 0.f, 0.f, 0.f};
    float4 a1 = {0.f, 0.f, 0.f, 0.f};

    if (STAGE == 0) {
#pragma unroll 2
        for (int i = grp; i < n; i += 8) {
            float4 e = s_e[i];
            uint2 b = Xb_in[(size_t)__float_as_int(e.x) * 32 + lane];
            float x0 = __uint_as_float(b.x << 16);
            float x1 = __uint_as_float(b.x & 0xffff0000u);
            float x2 = __uint_as_float(b.y << 16);
            float x3 = __uint_as_float(b.y & 0xffff0000u);
            a0.x += e.y * x0; a0.y += e.y * x1; a0.z += e.y * x2; a0.w += e.y * x3;
            a1.x += e.z * x0; a1.y += e.z * x1; a1.z += e.z * x2; a1.w += e.z * x3;
        }
    } else {
        const uint2* P0 = Xb_in;
        const uint2* P1 = Xb_in + (size_t)NN * 32;
#pragma unroll 2
        for (int i = grp; i < n; i += 8) {
            float4 e = s_e[i];
            int u = __float_as_int(e.x);
            uint2 b0 = P0[(size_t)u * 32 + lane];
            uint2 b1 = P1[(size_t)u * 32 + lane];
            a0.x += e.y * __uint_as_float(b0.x << 16);
            a0.y += e.y * __uint_as_float(b0.x & 0xffff0000u);
            a0.z += e.y * __uint_as_float(b0.y << 16);
            a0.w += e.y * __uint_as_float(b0.y & 0xffff0000u);
            a1.x += e.z * __uint_as_float(b1.x << 16);
            a1.y += e.z * __uint_as_float(b1.x & 0xffff0000u);
            a1.z += e.z * __uint_as_float(b1.y << 16);
            a1.w += e.z * __uint_as_float(b1.y & 0xffff0000u);
        }
    }

    s_acc[0][grp][lane] = a0;
    s_acc[1][grp][lane] = a1;
    __syncthreads();

    int c = tid >> 7, f = tid & 127;
    const float* base = (const float*)s_acc[c];      // [8][128]
    float s = 0.f;
#pragma unroll
    for (int g = 0; g < 8; ++g) s += base[g * 128 + f];

    float inv = 1.f;
    if (STAGE < 2 && n > 0) inv = 1.f / s_red[c];
    float val = s * inv;

    float* yrow = Y + ((size_t)c * NN + v) * YP;
    yrow[f] = val;
    if (STAGE < 2)
        Xb_out[((size_t)c * NN + v) * FINF + f] = (ushort)bf16bits(val);
    if (f == 0) {
        float dvn = s_red[2 + c] * inv;
        yrow[FINF] = dvn;
        if (STAGE < 2) Dd_out[c * NN + v] = dvn;
    }
}

// out[c,l,v,o] = relu( (sum_f Y_l[c][v][f] gW[c,f,o]) * inv_d + gb[c,o] )
__global__ __launch_bounds__(64) void gcn_out(
    const float* __restrict__ YA,
    const float* __restrict__ Y1,
    const float* __restrict__ Y2,
    const float* __restrict__ gW,   // [NC, FINF, FOUTF]
    const float* __restrict__ gb,   // [NC, FOUTF]
    float* __restrict__ out)        // [NC, 3, NN, FOUTF]
{
    const int grids_per_cl = NN / VB;
    int b   = blockIdx.x;
    int grp = b / grids_per_cl;           // cl = c*3 + l
    int v0  = (b % grids_per_cl) * VB;
    int c = grp / 3, l = grp % 3;
    const float* Y = (l == 0) ? YA : (l == 1) ? Y1 : Y2;

    __shared__ float s_y[VB][FINF];
    __shared__ float s_inv[VB];
    int t = threadIdx.x;

    for (int k = t; k < VB * (FINF / 4); k += 64) {
        int r = k >> 5, c4 = k & 31;
        float4 q = *(const float4*)(Y + ((size_t)c * NN + v0 + r) * YP + c4 * 4);
        *(float4*)&s_y[r][c4 * 4] = q;
    }
    if (t < VB) {
        float d = Y[((size_t)c * NN + v0 + t) * YP + FINF];
        s_inv[t] = (d != 0.f) ? (1.f / d) : 1.f;
    }
    __syncthreads();

    float acc[VB];
#pragma unroll
    for (int r = 0; r < VB; ++r) acc[r] = 0.f;

    const float* w = gW + (size_t)c * FINF * FOUTF + t;
    for (int f4 = 0; f4 < FINF / 4; ++f4) {
        float w0 = w[(size_t)(f4 * 4 + 0) * FOUTF];
        float w1 = w[(size_t)(f4 * 4 + 1) * FOUTF];
        float w2 = w[(size_t)(f4 * 4 + 2) * FOUTF];
        float w3 = w[(size_t)(f4 * 4 + 3) * FOUTF];
#pragma unroll
        for (int r = 0; r < VB; ++r) {
            float4 y4 = *(const float4*)&s_y[r][f4 * 4];
            acc[r] += y4.x * w0 + y4.y * w1 + y4.z * w2 + y4.w * w3;
        }
    }

    float bias = gb[c * FOUTF + t];
#pragma unroll
    for (int r = 0; r < VB; ++r) {
        float val = acc[r] * s_inv[r] + bias;
        out[((size_t)grp * NN + v0 + r) * FOUTF + t] = fmaxf(val, 0.f);
    }
}

extern "C" void kernel_launch(void* const* d_in, const int* in_sizes, int n_in,
                              void* d_out, int out_size, void* d_ws, size_t ws_size,
                              hipStream_t stream)
{
    const float* A     = (const float*)d_in[0];
    const float* h     = (const float*)d_in[1];
    const float* W1_0  = (const float*)d_in[2];
    const float* W2_0  = (const float*)d_in[3];
    const float* W1_1  = (const float*)d_in[4];
    const float* gW    = (const float*)d_in[5];
    const float* gb    = (const float*)d_in[6];
    float* out = (float*)d_out;

    char* ws = (char*)d_ws;
    int*    cnt2 = (int*)(ws);
    int*    eu   = (int*)(ws + 65536);
    float2* wA   = (float2*)(ws + 8454144);
    float2* wB   = (float2*)(ws + 25231360);
    float2* wC   = (float2*)(ws + 42008576);
    float*  YA   = (float*)(ws + 58785792);
    float*  Y1   = (float*)(ws + 63111168);
    float*  Y2   = (float*)(ws + 67436544);
    float*  DdA  = (float*)(ws + 71761920);
    float*  Dd1  = (float*)(ws + 71794688);
    uint2*  hb   = (uint2*)(ws + 71827456);
    ushort* XbA  = (ushort*)(ws + 72876032);
    ushort* Xb1  = (ushort*)(ws + 74973184);

    h2b<<<512, 256, 0, stream>>>((const float4*)h, hb);
    build_csc<<<256 * USPLIT, 256, 0, stream>>>(A, W1_0, W2_0, W1_1, cnt2, eu, wA, wB, wC);

    // Stage A: Y_A = RA^T [h|1]            (softmax weights wA, gather bf16 hb)
    spmm_col<0><<<NN, 256, 0, stream>>>(cnt2, eu, wA, hb, nullptr, YA, XbA, DdA);
    // Stage B: Y_1 = RB^T Y_A = H0^T [h|1] (softmax weights wB, gather bf16 XbA)
    spmm_col<1><<<NN, 256, 0, stream>>>(cnt2, eu, wB, (const uint2*)XbA, DdA, Y1, Xb1, Dd1);
    // Stage C: Y_2 = RB1^T Y_1 = H1^T [h|1] (raw weights wC, gather bf16 Xb1)
    spmm_col<2><<<NN, 256, 0, stream>>>(cnt2, eu, wC, (const uint2*)Xb1, Dd1, Y2, nullptr, nullptr);

    gcn_out<<<6 * NN / VB, 64, 0, stream>>>(YA, Y1, Y2, gW, gb, out);
}

// Round 5
// 224.452 us; speedup vs baseline: 1.1064x; 1.1064x over previous
//
#include <hip/hip_runtime.h>
#include <hip/hip_bf16.h>

#define NN    4096
#define NE    5
#define NC    2
#define FINF  128
#define FOUTF 64
#define CAP   384

// ---------------- workspace layout (bytes) ----------------
// cnt @ 0        : 16384
// eu  @ 16384    : NN*CAP*4 = 6291456
// wA  @ 6307840  : NN*CAP*8 = 12582912
// wB  @ 18890752 : 12582912
// wC  @ 31473664 : 12582912
// DdA @ 44056576 : 32768
// Dd1 @ 44089344 : 32768
// hb  @ 44122112 : NN*FINF*2 = 1048576
// XbA @ 45170688 : NC*NN*FINF*2 = 2097152
// Xb1 @ 47267840 : 2097152
// end ~ 49.4 MB

static __device__ __forceinline__ unsigned bf16bits(float x)
{
    __hip_bfloat16 t = __float2bfloat16(x);
    return (unsigned)*reinterpret_cast<unsigned short*>(&t);
}

// blocks 0..3: zero cnt; blocks 4..515: f32 h -> bf16 hb
__global__ __launch_bounds__(256) void init_misc(int4* __restrict__ cnt4,
                                                 const float4* __restrict__ h4,
                                                 uint2* __restrict__ hb)
{
    int b = blockIdx.x;
    if (b < 4) {
        cnt4[b * 256 + threadIdx.x] = int4{0, 0, 0, 0};
    } else {
        int i = (b - 4) * 256 + threadIdx.x;        // 131072 float4s
        float4 f = h4[i];
        uint2 r;
        r.x = bf16bits(f.x) | (bf16bits(f.y) << 16);
        r.y = bf16bits(f.z) | (bf16bits(f.w) << 16);
        hb[i] = r;
    }
}

// R3-style build: fully-coalesced float4 streaming reads of A (5 slices),
// global-atomic append into per-column SoA edge lists.
__global__ __launch_bounds__(256) void build_csc(
    const float* __restrict__ A,
    const float* __restrict__ W1_0,
    const float* __restrict__ W2_0,
    const float* __restrict__ W1_1,
    int*    __restrict__ cnt,
    int*    __restrict__ eu,
    float2* __restrict__ wA,
    float2* __restrict__ wB,
    float2* __restrict__ wC)
{
    float fA0[NE], fA1[NE], fB0[NE], fB1[NE], fC0[NE], fC1[NE];
#pragma unroll
    for (int e = 0; e < NE; ++e) {
        fA0[e] = W1_0[e];      fA1[e] = W1_0[NE + e];
        fB0[e] = W2_0[e];      fB1[e] = W2_0[NE + e];
        fC0[e] = W1_1[e];      fC1[e] = W1_1[NE + e];
    }

    const size_t S = (size_t)NN * NN / 4;   // float4 per e-slice
    const float4* A4 = (const float4*)A;
    size_t stride = (size_t)gridDim.x * blockDim.x;
    for (size_t i = (size_t)blockIdx.x * blockDim.x + threadIdx.x; i < S; i += stride) {
        float4 q0 = A4[i];
        float4 q1 = A4[i + S];
        float4 q2 = A4[i + 2 * S];
        float4 q3 = A4[i + 3 * S];
        float4 q4 = A4[i + 4 * S];
        int u  = (int)(i >> 10);            // 1024 float4 per row
        int v0 = ((int)i & 1023) << 2;
#define DO_COMP(comp, joff)                                                      \
        {                                                                        \
            float a0 = q0.comp, a1 = q1.comp, a2 = q2.comp,                      \
                  a3 = q3.comp, a4 = q4.comp;                                    \
            if (a0 != 0.f || a1 != 0.f || a2 != 0.f || a3 != 0.f || a4 != 0.f) { \
                float sA0 = fA0[0]*a0 + fA0[1]*a1 + fA0[2]*a2 + fA0[3]*a3 + fA0[4]*a4; \
                float sA1 = fA1[0]*a0 + fA1[1]*a1 + fA1[2]*a2 + fA1[3]*a3 + fA1[4]*a4; \
                float sB0 = fB0[0]*a0 + fB0[1]*a1 + fB0[2]*a2 + fB0[3]*a3 + fB0[4]*a4; \
                float sB1 = fB1[0]*a0 + fB1[1]*a1 + fB1[2]*a2 + fB1[3]*a3 + fB1[4]*a4; \
                float sC0 = fC0[0]*a0 + fC0[1]*a1 + fC0[2]*a2 + fC0[3]*a3 + fC0[4]*a4; \
                float sC1 = fC1[0]*a0 + fC1[1]*a1 + fC1[2]*a2 + fC1[3]*a3 + fC1[4]*a4; \
                int v = v0 + joff;                                               \
                int pos = atomicAdd(&cnt[v], 1);                                 \
                if (pos < CAP) {                                                 \
                    int slot = v * CAP + pos;                                    \
                    eu[slot] = u;                                                \
                    wA[slot] = float2{__expf(sA0), __expf(sA1)};                 \
                    wB[slot] = float2{__expf(sB0), __expf(sB1)};                 \
                    wC[slot] = float2{sC0, sC1};                                 \
                }                                                                \
            }                                                                    \
        }
        DO_COMP(x, 0)
        DO_COMP(y, 1)
        DO_COMP(z, 2)
        DO_COMP(w, 3)
#undef DO_COMP
    }
}

// One workgroup (256 threads) per column v; both channels; GCN epilogue fused.
// Phase 1: stage edges into LDS, reduce weight-sums + denominators.
// Phase 2: 8 edge-groups x 32 lanes, bf16x4 row gathers, LDS partials.
// Phase 3: tree-reduce -> y row (normalized), write bf16 panel + denom.
// Phase 4: 128x64 matvec with gW, bias, relu -> out[c][STAGE][v][:].
// STAGE 0: gather hb (shared row), softmax-norm, denom = sum(w) (-> 1)
// STAGE 1: gather bf16 panel/channel, softmax-norm, denom from Dd_in
// STAGE 2: gather bf16 panel/channel, no norm, denom from Dd_in
template<int STAGE>
__global__ __launch_bounds__(256) void spmm_col(
    const int*    __restrict__ cnt,
    const int*    __restrict__ eu,
    const float2* __restrict__ ew,
    const uint2*  __restrict__ Xb_in,   // stage0: [NN][32]; else [NC][NN][32]
    const float*  __restrict__ Dd_in,   // stages 1/2: [NC][NN]
    const float*  __restrict__ gW,      // [NC][FINF][FOUTF]
    const float*  __restrict__ gb,      // [NC][FOUTF]
    float*        __restrict__ out,     // [NC][3][NN][FOUTF]
    ushort*       __restrict__ Xb_out,  // stages 0/1
    float*        __restrict__ Dd_out)  // stages 0/1
{
    int v = blockIdx.x;
    int n = cnt[v];
    if (n > CAP) n = CAP;

    __shared__ float4 s_e[CAP];
    __shared__ float  s_red[4];          // sum0, sum1, d0, d1
    __shared__ float4 s_acc[NC][8][32];
    __shared__ float  s_y[NC][FINF];
    __shared__ float  s_inv[NC];

    int tid = threadIdx.x;
    if (tid < 4) s_red[tid] = 0.f;
    __syncthreads();

    float l0 = 0.f, l1 = 0.f, ld0 = 0.f, ld1 = 0.f;
    for (int i = tid; i < n; i += 256) {
        int    u = eu[v * CAP + i];
        float2 w = ew[v * CAP + i];
        s_e[i] = float4{__int_as_float(u), w.x, w.y, 0.f};
        l0 += w.x;
        l1 += w.y;
        if (STAGE != 0) {
            ld0 += w.x * Dd_in[u];
            ld1 += w.y * Dd_in[NN + u];
        }
    }
    if (STAGE == 0) { ld0 = l0; ld1 = l1; }

#pragma unroll
    for (int m = 32; m >= 1; m >>= 1) {
        l0  += __shfl_xor(l0,  m);
        l1  += __shfl_xor(l1,  m);
        ld0 += __shfl_xor(ld0, m);
        ld1 += __shfl_xor(ld1, m);
    }
    if ((tid & 63) == 0) {
        atomicAdd(&s_red[0], l0);
        atomicAdd(&s_red[1], l1);
        atomicAdd(&s_red[2], ld0);
        atomicAdd(&s_red[3], ld1);
    }
    __syncthreads();

    int grp = tid >> 5, lane = tid & 31;
    float4 a0 = {0.f, 0.f, 0.f, 0.f};
    float4 a1 = {0.f, 0.f, 0.f, 0.f};

    if (STAGE == 0) {
#pragma unroll 2
        for (int i = grp; i < n; i += 8) {
            float4 e = s_e[i];
            uint2 b = Xb_in[(size_t)__float_as_int(e.x) * 32 + lane];
            float x0 = __uint_as_float(b.x << 16);
            float x1 = __uint_as_float(b.x & 0xffff0000u);
            float x2 = __uint_as_float(b.y << 16);
            float x3 = __uint_as_float(b.y & 0xffff0000u);
            a0.x += e.y * x0; a0.y += e.y * x1; a0.z += e.y * x2; a0.w += e.y * x3;
            a1.x += e.z * x0; a1.y += e.z * x1; a1.z += e.z * x2; a1.w += e.z * x3;
        }
    } else {
        const uint2* P0 = Xb_in;
        const uint2* P1 = Xb_in + (size_t)NN * 32;
#pragma unroll 2
        for (int i = grp; i < n; i += 8) {
            float4 e = s_e[i];
            int u = __float_as_int(e.x);
            uint2 b0 = P0[(size_t)u * 32 + lane];
            uint2 b1 = P1[(size_t)u * 32 + lane];
            a0.x += e.y * __uint_as_float(b0.x << 16);
            a0.y += e.y * __uint_as_float(b0.x & 0xffff0000u);
            a0.z += e.y * __uint_as_float(b0.y << 16);
            a0.w += e.y * __uint_as_float(b0.y & 0xffff0000u);
            a1.x += e.z * __uint_as_float(b1.x << 16);
            a1.y += e.z * __uint_as_float(b1.x & 0xffff0000u);
            a1.z += e.z * __uint_as_float(b1.y << 16);
            a1.w += e.z * __uint_as_float(b1.y & 0xffff0000u);
        }
    }

    s_acc[0][grp][lane] = a0;
    s_acc[1][grp][lane] = a1;
    __syncthreads();

    int c = tid >> 7, f = tid & 127;
    {
        const float* base = (const float*)s_acc[c];      // [8][128]
        float s = 0.f;
#pragma unroll
        for (int g = 0; g < 8; ++g) s += base[g * 128 + f];

        float inv = 1.f;
        if (STAGE < 2 && n > 0) inv = 1.f / s_red[c];
        float val = s * inv;

        s_y[c][f] = val;
        if (STAGE < 2)
            Xb_out[((size_t)c * NN + v) * FINF + f] = (ushort)bf16bits(val);
        if (f == 0) {
            float dvn = s_red[2 + c] * inv;
            s_inv[c] = (dvn != 0.f) ? (1.f / dvn) : 1.f;
            if (STAGE < 2) Dd_out[c * NN + v] = dvn;
        }
    }
    __syncthreads();

    // Phase 4: fused GraphConv epilogue (128 threads: (c2, o))
    if (tid < 2 * FOUTF) {
        int c2 = tid >> 6, o = tid & 63;
        const float* w = gW + (size_t)c2 * FINF * FOUTF + o;
        const float* y = s_y[c2];
        float acc = 0.f;
#pragma unroll 8
        for (int f2 = 0; f2 < FINF; ++f2)
            acc += y[f2] * w[(size_t)f2 * FOUTF];
        float r = acc * s_inv[c2] + gb[c2 * FOUTF + o];
        out[(((size_t)c2 * 3 + STAGE) * NN + v) * FOUTF + o] = fmaxf(r, 0.f);
    }
}

extern "C" void kernel_launch(void* const* d_in, const int* in_sizes, int n_in,
                              void* d_out, int out_size, void* d_ws, size_t ws_size,
                              hipStream_t stream)
{
    const float* A     = (const float*)d_in[0];
    const float* h     = (const float*)d_in[1];
    const float* W1_0  = (const float*)d_in[2];
    const float* W2_0  = (const float*)d_in[3];
    const float* W1_1  = (const float*)d_in[4];
    const float* gW    = (const float*)d_in[5];
    const float* gb    = (const float*)d_in[6];
    float* out = (float*)d_out;

    char* ws = (char*)d_ws;
    int*    cnt = (int*)(ws);
    int*    eu  = (int*)(ws + 16384);
    float2* wA  = (float2*)(ws + 6307840);
    float2* wB  = (float2*)(ws + 18890752);
    float2* wC  = (float2*)(ws + 31473664);
    float*  DdA = (float*)(ws + 44056576);
    float*  Dd1 = (float*)(ws + 44089344);
    uint2*  hb  = (uint2*)(ws + 44122112);
    ushort* XbA = (ushort*)(ws + 45170688);
    ushort* Xb1 = (ushort*)(ws + 47267840);

    init_misc<<<516, 256, 0, stream>>>((int4*)cnt, (const float4*)h, hb);
    build_csc<<<2048, 256, 0, stream>>>(A, W1_0, W2_0, W1_1, cnt, eu, wA, wB, wC);

    // Stage A: Y_A = RA^T [h|1]            (softmax wA, gather bf16 hb)  -> out[:,0], XbA, DdA
    spmm_col<0><<<NN, 256, 0, stream>>>(cnt, eu, wA, hb, nullptr, gW, gb, out, XbA, DdA);
    // Stage B: Y_1 = H0^T [h|1]            (softmax wB, gather XbA)      -> out[:,1], Xb1, Dd1
    spmm_col<1><<<NN, 256, 0, stream>>>(cnt, eu, wB, (const uint2*)XbA, DdA, gW, gb, out, Xb1, Dd1);
    // Stage C: Y_2 = H1^T [h|1]            (raw wC, gather Xb1)          -> out[:,2]
    spmm_col<2><<<NN, 256, 0, stream>>>(cnt, eu, wC, (const uint2*)Xb1, Dd1, gW, gb, out, nullptr, nullptr);
}

// Round 6
// 212.116 us; speedup vs baseline: 1.1707x; 1.0582x over previous
//
#include <hip/hip_runtime.h>

#define NN    4096
#define NE    5
#define NC    2
#define FINF  128
#define FOUTF 64
#define CAP   384

// ---------------- workspace layout (bytes) ----------------
// cnt   @ 0        : 16384
// epack @ 16384    : NN*CAP*16 = 25165824   (int4: u, wA pair, wB pair, wC pair; fp16 weights)
// DdA   @ 25182208 : 32768
// Dd1   @ 25214976 : 32768
// hh    @ 25247744 : NN*FINF*2 = 1048576    (fp16 h panel)
// XhA   @ 26296320 : NC*NN*FINF*2 = 2097152
// Xh1   @ 28393472 : 2097152
// end ~ 30.5 MB

union f16u { unsigned short s; _Float16 h; };

static __device__ __forceinline__ unsigned short f2h(float x)
{
    f16u u; u.h = (_Float16)x; return u.s;
}
static __device__ __forceinline__ float lo16f(unsigned x)
{
    f16u u; u.s = (unsigned short)(x & 0xffff); return (float)u.h;
}
static __device__ __forceinline__ float hi16f(unsigned x)
{
    f16u u; u.s = (unsigned short)(x >> 16); return (float)u.h;
}
static __device__ __forceinline__ unsigned pack2h(float a, float b)
{
    return (unsigned)f2h(a) | ((unsigned)f2h(b) << 16);
}

// blocks 0..3: zero cnt; blocks 4..515: f32 h -> fp16 hh
__global__ __launch_bounds__(256) void init_misc(int4* __restrict__ cnt4,
                                                 const float4* __restrict__ h4,
                                                 uint2* __restrict__ hh)
{
    int b = blockIdx.x;
    if (b < 4) {
        cnt4[b * 256 + threadIdx.x] = int4{0, 0, 0, 0};
    } else {
        int i = (b - 4) * 256 + threadIdx.x;        // 131072 float4s
        float4 f = h4[i];
        uint2 r;
        r.x = pack2h(f.x, f.y);
        r.y = pack2h(f.z, f.w);
        hh[i] = r;
    }
}

// Coalesced float4 streaming reads of A (5 slices), global-atomic append,
// ONE 16-byte packed store per edge.
__global__ __launch_bounds__(256) void build_csc(
    const float* __restrict__ A,
    const float* __restrict__ W1_0,
    const float* __restrict__ W2_0,
    const float* __restrict__ W1_1,
    int*  __restrict__ cnt,
    int4* __restrict__ epack)
{
    float fA0[NE], fA1[NE], fB0[NE], fB1[NE], fC0[NE], fC1[NE];
#pragma unroll
    for (int e = 0; e < NE; ++e) {
        fA0[e] = W1_0[e];      fA1[e] = W1_0[NE + e];
        fB0[e] = W2_0[e];      fB1[e] = W2_0[NE + e];
        fC0[e] = W1_1[e];      fC1[e] = W1_1[NE + e];
    }

    const size_t S = (size_t)NN * NN / 4;   // float4 per e-slice
    const float4* A4 = (const float4*)A;
    size_t stride = (size_t)gridDim.x * blockDim.x;
    for (size_t i = (size_t)blockIdx.x * blockDim.x + threadIdx.x; i < S; i += stride) {
        float4 q0 = A4[i];
        float4 q1 = A4[i + S];
        float4 q2 = A4[i + 2 * S];
        float4 q3 = A4[i + 3 * S];
        float4 q4 = A4[i + 4 * S];
        int u  = (int)(i >> 10);            // 1024 float4 per row
        int v0 = ((int)i & 1023) << 2;
#define DO_COMP(comp, joff)                                                      \
        {                                                                        \
            float a0 = q0.comp, a1 = q1.comp, a2 = q2.comp,                      \
                  a3 = q3.comp, a4 = q4.comp;                                    \
            if (a0 != 0.f || a1 != 0.f || a2 != 0.f || a3 != 0.f || a4 != 0.f) { \
                float sA0 = fA0[0]*a0 + fA0[1]*a1 + fA0[2]*a2 + fA0[3]*a3 + fA0[4]*a4; \
                float sA1 = fA1[0]*a0 + fA1[1]*a1 + fA1[2]*a2 + fA1[3]*a3 + fA1[4]*a4; \
                float sB0 = fB0[0]*a0 + fB0[1]*a1 + fB0[2]*a2 + fB0[3]*a3 + fB0[4]*a4; \
                float sB1 = fB1[0]*a0 + fB1[1]*a1 + fB1[2]*a2 + fB1[3]*a3 + fB1[4]*a4; \
                float sC0 = fC0[0]*a0 + fC0[1]*a1 + fC0[2]*a2 + fC0[3]*a3 + fC0[4]*a4; \
                float sC1 = fC1[0]*a0 + fC1[1]*a1 + fC1[2]*a2 + fC1[3]*a3 + fC1[4]*a4; \
                int v = v0 + joff;                                               \
                int pos = atomicAdd(&cnt[v], 1);                                 \
                if (pos < CAP) {                                                 \
                    int4 rec;                                                    \
                    rec.x = u;                                                   \
                    rec.y = (int)pack2h(__expf(sA0), __expf(sA1));               \
                    rec.z = (int)pack2h(__expf(sB0), __expf(sB1));               \
                    rec.w = (int)pack2h(sC0, sC1);                               \
                    epack[v * CAP + pos] = rec;                                  \
                }                                                                \
            }                                                                    \
        }
        DO_COMP(x, 0)
        DO_COMP(y, 1)
        DO_COMP(z, 2)
        DO_COMP(w, 3)
#undef DO_COMP
    }
}

// One workgroup (256 threads) per column v; both channels; GCN epilogue fused.
// Phase 1: stage edges into LDS (one int4/edge), reduce weight-sums + denoms.
// Phase 2: 8 edge-groups x 32 lanes, fp16x4 row gathers, LDS partials.
// Phase 3: tree-reduce -> y row (normalized), write fp16 panel + denom.
// Phase 4: 128x64 matvec with gW, bias, relu -> out[c][STAGE][v][:].
template<int STAGE>
__global__ __launch_bounds__(256) void spmm_col(
    const int*   __restrict__ cnt,
    const int4*  __restrict__ epack,
    const uint2* __restrict__ Xh_in,    // stage0: [NN][32]; else [NC][NN][32]
    const float* __restrict__ Dd_in,    // stages 1/2: [NC][NN]
    const float* __restrict__ gW,       // [NC][FINF][FOUTF]
    const float* __restrict__ gb,       // [NC][FOUTF]
    float*       __restrict__ out,      // [NC][3][NN][FOUTF]
    unsigned short* __restrict__ Xh_out,// stages 0/1
    float*       __restrict__ Dd_out)   // stages 0/1
{
    int v = blockIdx.x;
    int n = cnt[v];
    if (n > CAP) n = CAP;

    __shared__ float4 s_e[CAP];          // {u bits, w0, w1, pad}
    __shared__ float  s_red[4];          // sum0, sum1, d0, d1
    __shared__ float4 s_acc[NC][8][32];
    __shared__ float  s_y[NC][FINF];
    __shared__ float  s_inv[NC];

    int tid = threadIdx.x;
    if (tid < 4) s_red[tid] = 0.f;
    __syncthreads();

    float l0 = 0.f, l1 = 0.f, ld0 = 0.f, ld1 = 0.f;
    for (int i = tid; i < n; i += 256) {
        int4 E = epack[v * CAP + i];
        unsigned wb = (unsigned)((STAGE == 0) ? E.y : (STAGE == 1) ? E.z : E.w);
        float w0 = lo16f(wb), w1 = hi16f(wb);
        s_e[i] = float4{__int_as_float(E.x), w0, w1, 0.f};
        l0 += w0;
        l1 += w1;
        if (STAGE != 0) {
            ld0 += w0 * Dd_in[E.x];
            ld1 += w1 * Dd_in[NN + E.x];
        }
    }
    if (STAGE == 0) { ld0 = l0; ld1 = l1; }

#pragma unroll
    for (int m = 32; m >= 1; m >>= 1) {
        l0  += __shfl_xor(l0,  m);
        l1  += __shfl_xor(l1,  m);
        ld0 += __shfl_xor(ld0, m);
        ld1 += __shfl_xor(ld1, m);
    }
    if ((tid & 63) == 0) {
        atomicAdd(&s_red[0], l0);
        atomicAdd(&s_red[1], l1);
        atomicAdd(&s_red[2], ld0);
        atomicAdd(&s_red[3], ld1);
    }
    __syncthreads();

    int grp = tid >> 5, lane = tid & 31;
    float4 a0 = {0.f, 0.f, 0.f, 0.f};
    float4 a1 = {0.f, 0.f, 0.f, 0.f};

    if (STAGE == 0) {
#pragma unroll 2
        for (int i = grp; i < n; i += 8) {
            float4 e = s_e[i];
            uint2 b = Xh_in[(size_t)__float_as_int(e.x) * 32 + lane];
            float x0 = lo16f(b.x), x1 = hi16f(b.x);
            float x2 = lo16f(b.y), x3 = hi16f(b.y);
            a0.x += e.y * x0; a0.y += e.y * x1; a0.z += e.y * x2; a0.w += e.y * x3;
            a1.x += e.z * x0; a1.y += e.z * x1; a1.z += e.z * x2; a1.w += e.z * x3;
        }
    } else {
        const uint2* P0 = Xh_in;
        const uint2* P1 = Xh_in + (size_t)NN * 32;
#pragma unroll 2
        for (int i = grp; i < n; i += 8) {
            float4 e = s_e[i];
            int u = __float_as_int(e.x);
            uint2 b0 = P0[(size_t)u * 32 + lane];
            uint2 b1 = P1[(size_t)u * 32 + lane];
            a0.x += e.y * lo16f(b0.x); a0.y += e.y * hi16f(b0.x);
            a0.z += e.y * lo16f(b0.y); a0.w += e.y * hi16f(b0.y);
            a1.x += e.z * lo16f(b1.x); a1.y += e.z * hi16f(b1.x);
            a1.z += e.z * lo16f(b1.y); a1.w += e.z * hi16f(b1.y);
        }
    }

    s_acc[0][grp][lane] = a0;
    s_acc[1][grp][lane] = a1;
    __syncthreads();

    int c = tid >> 7, f = tid & 127;
    {
        const float* base = (const float*)s_acc[c];      // [8][128]
        float s = 0.f;
#pragma unroll
        for (int g = 0; g < 8; ++g) s += base[g * 128 + f];

        float inv = 1.f;
        if (STAGE < 2 && n > 0) inv = 1.f / s_red[c];
        float val = s * inv;

        s_y[c][f] = val;
        if (STAGE < 2)
            Xh_out[((size_t)c * NN + v) * FINF + f] = f2h(val);
        if (f == 0) {
            float dvn = s_red[2 + c] * inv;
            s_inv[c] = (dvn != 0.f) ? (1.f / dvn) : 1.f;
            if (STAGE < 2) Dd_out[c * NN + v] = dvn;
        }
    }
    __syncthreads();

    // Phase 4: fused GraphConv epilogue (128 threads: (c2, o))
    if (tid < 2 * FOUTF) {
        int c2 = tid >> 6, o = tid & 63;
        const float* w = gW + (size_t)c2 * FINF * FOUTF + o;
        const float* y = s_y[c2];
        float acc = 0.f;
#pragma unroll 8
        for (int f2 = 0; f2 < FINF; ++f2)
            acc += y[f2] * w[(size_t)f2 * FOUTF];
        float r = acc * s_inv[c2] + gb[c2 * FOUTF + o];
        out[(((size_t)c2 * 3 + STAGE) * NN + v) * FOUTF + o] = fmaxf(r, 0.f);
    }
}

extern "C" void kernel_launch(void* const* d_in, const int* in_sizes, int n_in,
                              void* d_out, int out_size, void* d_ws, size_t ws_size,
                              hipStream_t stream)
{
    const float* A     = (const float*)d_in[0];
    const float* h     = (const float*)d_in[1];
    const float* W1_0  = (const float*)d_in[2];
    const float* W2_0  = (const float*)d_in[3];
    const float* W1_1  = (const float*)d_in[4];
    const float* gW    = (const float*)d_in[5];
    const float* gb    = (const float*)d_in[6];
    float* out = (float*)d_out;

    char* ws = (char*)d_ws;
    int*            cnt   = (int*)(ws);
    int4*           epack = (int4*)(ws + 16384);
    float*          DdA   = (float*)(ws + 25182208);
    float*          Dd1   = (float*)(ws + 25214976);
    uint2*          hh    = (uint2*)(ws + 25247744);
    unsigned short* XhA   = (unsigned short*)(ws + 26296320);
    unsigned short* Xh1   = (unsigned short*)(ws + 28393472);

    init_misc<<<516, 256, 0, stream>>>((int4*)cnt, (const float4*)h, hh);
    build_csc<<<2048, 256, 0, stream>>>(A, W1_0, W2_0, W1_1, cnt, epack);

    // Stage A: softmax wA, gather fp16 hh -> out[:,0], XhA, DdA
    spmm_col<0><<<NN, 256, 0, stream>>>(cnt, epack, hh, nullptr, gW, gb, out, XhA, DdA);
    // Stage B: softmax wB, gather XhA     -> out[:,1], Xh1, Dd1
    spmm_col<1><<<NN, 256, 0, stream>>>(cnt, epack, (const uint2*)XhA, DdA, gW, gb, out, Xh1, Dd1);
    // Stage C: raw wC, gather Xh1         -> out[:,2]
    spmm_col<2><<<NN, 256, 0, stream>>>(cnt, epack, (const uint2*)Xh1, Dd1, gW, gb, out, nullptr, nullptr);
}